// Round 1
// baseline (5893.513 us; speedup 1.0000x reference)
//
#include <hip/hip_runtime.h>
#include <hip/hip_bf16.h>

#define HID 128
#define OUT_DIM 112

// ---- transpose W_l (128x128) and W_r (128x128) into concatenated Wt[256][128]
__global__ __launch_bounds__(256) void transpose_cat_kernel(
    const float* __restrict__ Wl, const float* __restrict__ Wr,
    float* __restrict__ wt) {
  int i = blockIdx.x * 256 + threadIdx.x;  // 0..32767
  int k = i >> 7;                          // 0..255
  int o = i & 127;
  float v = (k < 128) ? Wl[o * 128 + k] : Wr[o * 128 + (k - 128)];
  wt[i] = v;
}

// ---- transpose W_out (112x128) into Wt[128][128] (padded with zeros, o>=112)
__global__ __launch_bounds__(256) void transpose_out_kernel(
    const float* __restrict__ Wo, float* __restrict__ wt) {
  int i = blockIdx.x * 256 + threadIdx.x;  // 0..16383
  int k = i >> 7;                          // 0..127
  int o = i & 127;
  wt[i] = (o < OUT_DIM) ? Wo[o * 128 + k] : 0.0f;
}

// ---- degree count (float atomics; counts are small integers, exact)
__global__ __launch_bounds__(256) void count_deg_kernel(
    const int* __restrict__ dst, float* __restrict__ deg, int e) {
  int i = blockIdx.x * 256 + threadIdx.x;
  if (i < e) unsafeAtomicAdd(&deg[dst[i]], 1.0f);
}

__global__ __launch_bounds__(256) void inv_deg_kernel(float* __restrict__ deg, int n) {
  int i = blockIdx.x * 256 + threadIdx.x;
  if (i < n) deg[i] = 1.0f / fmaxf(deg[i], 1.0f);
}

// ---- scatter-add: 32 threads per edge, float4 chunks, HW fp32 atomics
__global__ __launch_bounds__(256) void scatter_kernel(
    const float* __restrict__ xin, const int* __restrict__ src,
    const int* __restrict__ dst, float* __restrict__ agg, int e) {
  long long idx = (long long)blockIdx.x * 256 + threadIdx.x;
  if (idx >= (long long)e * 32) return;
  int edge = (int)(idx >> 5);
  int c = (int)(idx & 31);
  int s = src[edge];
  int d = dst[edge];
  float4 v = ((const float4*)(xin + (size_t)s * 128))[c];
  float* p = agg + (size_t)d * 128 + (size_t)c * 4;
  unsafeAtomicAdd(p + 0, v.x);
  unsafeAtomicAdd(p + 1, v.y);
  unsafeAtomicAdd(p + 2, v.z);
  unsafeAtomicAdd(p + 3, v.w);
}

// ---- fused SAGE linear: out = relu( (agg*dinv) @ Wl^T + b + xin @ Wr^T )
// z = [mean | x] (K=256); wt is Wt_cat[k][o]. 64 nodes/block, 256 threads,
// each thread: 8 nodes x 4 outputs.
__global__ __launch_bounds__(256) void lin_kernel(
    const float* __restrict__ agg, const float* __restrict__ dinv,
    const float* __restrict__ xin, const float* __restrict__ wt,
    const float* __restrict__ bias, float* __restrict__ outp, int n) {
  __shared__ float z[64][256];
  const int t = threadIdx.x;
  const int block0 = blockIdx.x * 64;
#pragma unroll
  for (int i = 0; i < 16; ++i) {
    int f4 = i * 256 + t;     // 0..4095 float4 slots
    int row = f4 >> 6;        // 64 float4 per row
    int col4 = f4 & 63;
    int node = block0 + row;
    float4 v = make_float4(0.f, 0.f, 0.f, 0.f);
    if (node < n) {
      if (col4 < 32) {
        v = ((const float4*)(agg + (size_t)node * 128))[col4];
        float s = dinv[node];
        v.x *= s; v.y *= s; v.z *= s; v.w *= s;
      } else {
        v = ((const float4*)(xin + (size_t)node * 128))[col4 - 32];
      }
    }
    *((float4*)&z[row][col4 * 4]) = v;
  }
  __syncthreads();
  const int ncol = t & 31;
  const int nrow = t >> 5;
  const int o = ncol * 4;
  float4 bb = *((const float4*)(bias + o));
  float acc[8][4];
#pragma unroll
  for (int j = 0; j < 8; ++j) {
    acc[j][0] = bb.x; acc[j][1] = bb.y; acc[j][2] = bb.z; acc[j][3] = bb.w;
  }
#pragma unroll 4
  for (int k = 0; k < 256; ++k) {
    float4 w = *((const float4*)(wt + k * 128 + o));
#pragma unroll
    for (int j = 0; j < 8; ++j) {
      float zz = z[nrow * 8 + j][k];
      acc[j][0] += zz * w.x;
      acc[j][1] += zz * w.y;
      acc[j][2] += zz * w.z;
      acc[j][3] += zz * w.w;
    }
  }
#pragma unroll
  for (int j = 0; j < 8; ++j) {
    int node = block0 + nrow * 8 + j;
    if (node < n) {
      float4 r;
      r.x = fmaxf(acc[j][0], 0.f);
      r.y = fmaxf(acc[j][1], 0.f);
      r.z = fmaxf(acc[j][2], 0.f);
      r.w = fmaxf(acc[j][3], 0.f);
      *((float4*)(outp + (size_t)node * 128 + o)) = r;
    }
  }
}

// ---- output projection: out = h2 @ W_out^T + b_out (N padded to 128, store 112)
__global__ __launch_bounds__(256) void out_kernel(
    const float* __restrict__ h2, const float* __restrict__ wt,
    const float* __restrict__ bias, float* __restrict__ outp, int n) {
  __shared__ float z[64][128];
  const int t = threadIdx.x;
  const int block0 = blockIdx.x * 64;
#pragma unroll
  for (int i = 0; i < 8; ++i) {
    int f4 = i * 256 + t;     // 0..2047
    int row = f4 >> 5;        // 32 float4 per row
    int col4 = f4 & 31;
    int node = block0 + row;
    float4 v = make_float4(0.f, 0.f, 0.f, 0.f);
    if (node < n) v = ((const float4*)(h2 + (size_t)node * 128))[col4];
    *((float4*)&z[row][col4 * 4]) = v;
  }
  __syncthreads();
  const int ncol = t & 31;
  const int nrow = t >> 5;
  const int o = ncol * 4;
  float4 bb = make_float4(0.f, 0.f, 0.f, 0.f);
  if (ncol < 28) bb = *((const float4*)(bias + o));
  float acc[8][4];
#pragma unroll
  for (int j = 0; j < 8; ++j) {
    acc[j][0] = bb.x; acc[j][1] = bb.y; acc[j][2] = bb.z; acc[j][3] = bb.w;
  }
#pragma unroll 4
  for (int k = 0; k < 128; ++k) {
    float4 w = *((const float4*)(wt + k * 128 + o));
#pragma unroll
    for (int j = 0; j < 8; ++j) {
      float zz = z[nrow * 8 + j][k];
      acc[j][0] += zz * w.x;
      acc[j][1] += zz * w.y;
      acc[j][2] += zz * w.z;
      acc[j][3] += zz * w.w;
    }
  }
  if (ncol < 28) {
#pragma unroll
    for (int j = 0; j < 8; ++j) {
      int node = block0 + nrow * 8 + j;
      if (node < n) {
        float4 r;
        r.x = acc[j][0]; r.y = acc[j][1]; r.z = acc[j][2]; r.w = acc[j][3];
        *((float4*)(outp + (size_t)node * OUT_DIM + o)) = r;
      }
    }
  }
}

extern "C" void kernel_launch(void* const* d_in, const int* in_sizes, int n_in,
                              void* d_out, int out_size, void* d_ws, size_t ws_size,
                              hipStream_t stream) {
  const float* x     = (const float*)d_in[0];
  const int*   ei    = (const int*)d_in[1];
  const float* W_l1  = (const float*)d_in[2];
  const float* b_l1  = (const float*)d_in[3];
  const float* W_r1  = (const float*)d_in[4];
  const float* W_l2  = (const float*)d_in[5];
  const float* b_l2  = (const float*)d_in[6];
  const float* W_r2  = (const float*)d_in[7];
  const float* W_out = (const float*)d_in[8];
  const float* b_out = (const float*)d_in[9];

  const int N = in_sizes[0] / 128;
  const int E = in_sizes[1] / 2;
  const int* src = ei;
  const int* dst = ei + E;

  float* AGG = (float*)d_ws;               // N*128
  float* H   = AGG + (size_t)N * 128;      // N*128
  float* DEG = H + (size_t)N * 128;        // N
  float* WT1 = DEG + N;                    // 256*128
  float* WT2 = WT1 + 256 * 128;            // 256*128
  float* WTO = WT2 + 256 * 128;            // 128*128 (padded)

  hipMemsetAsync(AGG, 0, (size_t)N * 128 * sizeof(float), stream);
  hipMemsetAsync(DEG, 0, (size_t)N * sizeof(float), stream);

  transpose_cat_kernel<<<128, 256, 0, stream>>>(W_l1, W_r1, WT1);
  transpose_cat_kernel<<<128, 256, 0, stream>>>(W_l2, W_r2, WT2);
  transpose_out_kernel<<<64, 256, 0, stream>>>(W_out, WTO);

  count_deg_kernel<<<(E + 255) / 256, 256, 0, stream>>>(dst, DEG, E);
  inv_deg_kernel<<<(N + 255) / 256, 256, 0, stream>>>(DEG, N);

  long long sthreads = (long long)E * 32;
  int sblocks = (int)((sthreads + 255) / 256);
  int lblocks = (N + 63) / 64;

  // layer 1
  scatter_kernel<<<sblocks, 256, 0, stream>>>(x, src, dst, AGG, E);
  lin_kernel<<<lblocks, 256, 0, stream>>>(AGG, DEG, x, WT1, b_l1, H, N);

  // layer 2 (h2 written in-place into AGG)
  hipMemsetAsync(AGG, 0, (size_t)N * 128 * sizeof(float), stream);
  scatter_kernel<<<sblocks, 256, 0, stream>>>(H, src, dst, AGG, E);
  lin_kernel<<<lblocks, 256, 0, stream>>>(AGG, DEG, H, WT2, b_l2, AGG, N);

  // output projection
  out_kernel<<<lblocks, 256, 0, stream>>>(AGG, WTO, b_out, (float*)d_out, N);
}

// Round 2
// 909.147 us; speedup vs baseline: 6.4825x; 6.4825x over previous
//
#include <hip/hip_runtime.h>
#include <hip/hip_bf16.h>

#define HID 128
#define OUT_DIM 112

// ---- transpose W_l (128x128) and W_r (128x128) into concatenated Wt[256][128]
__global__ __launch_bounds__(256) void transpose_cat_kernel(
    const float* __restrict__ Wl, const float* __restrict__ Wr,
    float* __restrict__ wt) {
  int i = blockIdx.x * 256 + threadIdx.x;  // 0..32767
  int k = i >> 7;                          // 0..255
  int o = i & 127;
  float v = (k < 128) ? Wl[o * 128 + k] : Wr[o * 128 + (k - 128)];
  wt[i] = v;
}

// ---- transpose W_out (112x128) into Wt[128][128] (padded with zeros, o>=112)
__global__ __launch_bounds__(256) void transpose_out_kernel(
    const float* __restrict__ Wo, float* __restrict__ wt) {
  int i = blockIdx.x * 256 + threadIdx.x;  // 0..16383
  int k = i >> 7;                          // 0..127
  int o = i & 127;
  wt[i] = (o < OUT_DIM) ? Wo[o * 128 + k] : 0.0f;
}

// ---- CSR build step 1: integer degree count
__global__ __launch_bounds__(256) void deg_kernel(
    const int* __restrict__ dst, int* __restrict__ deg, int e) {
  int i = blockIdx.x * 256 + threadIdx.x;
  if (i < e) atomicAdd(&deg[dst[i]], 1);
}

// ---- CSR build step 2: exclusive prefix sum (single block, 1024 threads,
// wave-shuffle scan + cross-wave LDS combine; ~3 barriers per 1024-chunk)
__global__ __launch_bounds__(1024) void scan_kernel(
    const int* __restrict__ deg, int* __restrict__ rowstart,
    float* __restrict__ dinv, int n) {
  __shared__ int wsum[16];
  __shared__ int carry_s;
  const int lane = threadIdx.x & 63;
  const int wid = threadIdx.x >> 6;
  if (threadIdx.x == 0) carry_s = 0;
  __syncthreads();
  for (int base = 0; base < n; base += 1024) {
    int i = base + threadIdx.x;
    int v = (i < n) ? deg[i] : 0;
    // inclusive scan within wave
    int s = v;
#pragma unroll
    for (int off = 1; off < 64; off <<= 1) {
      int t = __shfl_up(s, off, 64);
      if (lane >= off) s += t;
    }
    if (lane == 63) wsum[wid] = s;
    int c = carry_s;  // stable: last write was before previous barrier
    __syncthreads();
    if (wid == 0) {
      int ws = (lane < 16) ? wsum[lane] : 0;
#pragma unroll
      for (int off = 1; off < 16; off <<= 1) {
        int t = __shfl_up(ws, off, 64);
        if (lane >= off) ws += t;
      }
      if (lane < 16) wsum[lane] = ws;  // inclusive wave prefix
    }
    __syncthreads();
    int wbase = (wid > 0) ? wsum[wid - 1] : 0;
    int incl = s + wbase;
    if (i < n) {
      rowstart[i] = c + incl - v;  // exclusive
      dinv[i] = 1.0f / (float)max(v, 1);
    }
    __syncthreads();
    if (threadIdx.x == 0) carry_s = c + wsum[15];
    __syncthreads();
  }
  if (threadIdx.x == 0) rowstart[n] = carry_s;
}

// ---- CSR build step 3: fill edge lists via atomic cursors
__global__ __launch_bounds__(256) void fill_kernel(
    const int* __restrict__ src, const int* __restrict__ dst,
    int* __restrict__ cursor, int* __restrict__ csr_src, int e) {
  int i = blockIdx.x * 256 + threadIdx.x;
  if (i < e) {
    int pos = atomicAdd(&cursor[dst[i]], 1);
    csr_src[pos] = src[i];
  }
}

// ---- gather-mean aggregation: one wave per node, float2 per lane
__global__ __launch_bounds__(256) void agg_kernel(
    const float* __restrict__ xin, const int* __restrict__ csr_src,
    const int* __restrict__ rowstart, const float* __restrict__ dinv,
    float* __restrict__ agg, int n) {
  int node = blockIdx.x * 4 + (threadIdx.x >> 6);
  int lane = threadIdx.x & 63;
  if (node >= n) return;
  int start = rowstart[node];
  int end = rowstart[node + 1];
  float ax = 0.f, ay = 0.f;
  int e = start;
  for (; e + 4 <= end; e += 4) {
    int s0 = csr_src[e + 0];
    int s1 = csr_src[e + 1];
    int s2 = csr_src[e + 2];
    int s3 = csr_src[e + 3];
    float2 v0 = ((const float2*)(xin + (size_t)s0 * 128))[lane];
    float2 v1 = ((const float2*)(xin + (size_t)s1 * 128))[lane];
    float2 v2 = ((const float2*)(xin + (size_t)s2 * 128))[lane];
    float2 v3 = ((const float2*)(xin + (size_t)s3 * 128))[lane];
    ax += (v0.x + v1.x) + (v2.x + v3.x);
    ay += (v0.y + v1.y) + (v2.y + v3.y);
  }
  for (; e < end; ++e) {
    int s0 = csr_src[e];
    float2 v0 = ((const float2*)(xin + (size_t)s0 * 128))[lane];
    ax += v0.x;
    ay += v0.y;
  }
  float sc = dinv[node];
  float2 r;
  r.x = ax * sc;
  r.y = ay * sc;
  ((float2*)(agg + (size_t)node * 128))[lane] = r;
}

// ---- fused SAGE linear: out = relu( mean @ Wl^T + b + xin @ Wr^T )
// z = [mean | x] (K=256); wt is Wt_cat[k][o]. 64 nodes/block, 256 threads,
// each thread: 8 nodes x 4 outputs. In-place safe (block reads its own rows
// to LDS before any write).
__global__ __launch_bounds__(256) void lin_kernel(
    const float* __restrict__ mean, const float* __restrict__ xin,
    const float* __restrict__ wt, const float* __restrict__ bias,
    float* __restrict__ outp, int n) {
  __shared__ float z[64][256];
  const int t = threadIdx.x;
  const int block0 = blockIdx.x * 64;
#pragma unroll
  for (int i = 0; i < 16; ++i) {
    int f4 = i * 256 + t;     // 0..4095 float4 slots
    int row = f4 >> 6;        // 64 float4 per row
    int col4 = f4 & 63;
    int node = block0 + row;
    float4 v = make_float4(0.f, 0.f, 0.f, 0.f);
    if (node < n) {
      if (col4 < 32) {
        v = ((const float4*)(mean + (size_t)node * 128))[col4];
      } else {
        v = ((const float4*)(xin + (size_t)node * 128))[col4 - 32];
      }
    }
    *((float4*)&z[row][col4 * 4]) = v;
  }
  __syncthreads();
  const int ncol = t & 31;
  const int nrow = t >> 5;
  const int o = ncol * 4;
  float4 bb = *((const float4*)(bias + o));
  float acc[8][4];
#pragma unroll
  for (int j = 0; j < 8; ++j) {
    acc[j][0] = bb.x; acc[j][1] = bb.y; acc[j][2] = bb.z; acc[j][3] = bb.w;
  }
#pragma unroll 4
  for (int k = 0; k < 256; ++k) {
    float4 w = *((const float4*)(wt + k * 128 + o));
#pragma unroll
    for (int j = 0; j < 8; ++j) {
      float zz = z[nrow * 8 + j][k];
      acc[j][0] += zz * w.x;
      acc[j][1] += zz * w.y;
      acc[j][2] += zz * w.z;
      acc[j][3] += zz * w.w;
    }
  }
#pragma unroll
  for (int j = 0; j < 8; ++j) {
    int node = block0 + nrow * 8 + j;
    if (node < n) {
      float4 r;
      r.x = fmaxf(acc[j][0], 0.f);
      r.y = fmaxf(acc[j][1], 0.f);
      r.z = fmaxf(acc[j][2], 0.f);
      r.w = fmaxf(acc[j][3], 0.f);
      *((float4*)(outp + (size_t)node * 128 + o)) = r;
    }
  }
}

// ---- output projection: out = h2 @ W_out^T + b_out (store 112 of 128)
__global__ __launch_bounds__(256) void out_kernel(
    const float* __restrict__ h2, const float* __restrict__ wt,
    const float* __restrict__ bias, float* __restrict__ outp, int n) {
  __shared__ float z[64][128];
  const int t = threadIdx.x;
  const int block0 = blockIdx.x * 64;
#pragma unroll
  for (int i = 0; i < 8; ++i) {
    int f4 = i * 256 + t;     // 0..2047
    int row = f4 >> 5;        // 32 float4 per row
    int col4 = f4 & 31;
    int node = block0 + row;
    float4 v = make_float4(0.f, 0.f, 0.f, 0.f);
    if (node < n) v = ((const float4*)(h2 + (size_t)node * 128))[col4];
    *((float4*)&z[row][col4 * 4]) = v;
  }
  __syncthreads();
  const int ncol = t & 31;
  const int nrow = t >> 5;
  const int o = ncol * 4;
  float4 bb = make_float4(0.f, 0.f, 0.f, 0.f);
  if (ncol < 28) bb = *((const float4*)(bias + o));
  float acc[8][4];
#pragma unroll
  for (int j = 0; j < 8; ++j) {
    acc[j][0] = bb.x; acc[j][1] = bb.y; acc[j][2] = bb.z; acc[j][3] = bb.w;
  }
#pragma unroll 4
  for (int k = 0; k < 128; ++k) {
    float4 w = *((const float4*)(wt + k * 128 + o));
#pragma unroll
    for (int j = 0; j < 8; ++j) {
      float zz = z[nrow * 8 + j][k];
      acc[j][0] += zz * w.x;
      acc[j][1] += zz * w.y;
      acc[j][2] += zz * w.z;
      acc[j][3] += zz * w.w;
    }
  }
  if (ncol < 28) {
#pragma unroll
    for (int j = 0; j < 8; ++j) {
      int node = block0 + nrow * 8 + j;
      if (node < n) {
        float4 r;
        r.x = acc[j][0]; r.y = acc[j][1]; r.z = acc[j][2]; r.w = acc[j][3];
        *((float4*)(outp + (size_t)node * OUT_DIM + o)) = r;
      }
    }
  }
}

extern "C" void kernel_launch(void* const* d_in, const int* in_sizes, int n_in,
                              void* d_out, int out_size, void* d_ws, size_t ws_size,
                              hipStream_t stream) {
  const float* x     = (const float*)d_in[0];
  const int*   ei    = (const int*)d_in[1];
  const float* W_l1  = (const float*)d_in[2];
  const float* b_l1  = (const float*)d_in[3];
  const float* W_r1  = (const float*)d_in[4];
  const float* W_l2  = (const float*)d_in[5];
  const float* b_l2  = (const float*)d_in[6];
  const float* W_r2  = (const float*)d_in[7];
  const float* W_out = (const float*)d_in[8];
  const float* b_out = (const float*)d_in[9];

  const int N = in_sizes[0] / 128;
  const int E = in_sizes[1] / 2;
  const int* src = ei;
  const int* dst = ei + E;

  float* AGG  = (float*)d_ws;               // N*128 f32
  float* H    = AGG + (size_t)N * 128;      // N*128 f32
  float* DINV = H + (size_t)N * 128;        // N f32
  float* WT1  = DINV + N;                   // 256*128 f32
  float* WT2  = WT1 + 256 * 128;            // 256*128 f32
  float* WTO  = WT2 + 256 * 128;            // 128*128 f32
  int* DEG      = (int*)(WTO + 128 * 128);  // N i32 (also scan input)
  int* ROWSTART = DEG + N;                  // N+1 i32
  int* CURSOR   = ROWSTART + N + 1;         // N i32
  int* CSRSRC   = CURSOR + N;               // E i32

  // ---- CSR build (once; reused by both layers)
  hipMemsetAsync(DEG, 0, (size_t)N * sizeof(int), stream);
  deg_kernel<<<(E + 255) / 256, 256, 0, stream>>>(dst, DEG, E);
  scan_kernel<<<1, 1024, 0, stream>>>(DEG, ROWSTART, DINV, N);
  hipMemcpyAsync(CURSOR, ROWSTART, (size_t)N * sizeof(int),
                 hipMemcpyDeviceToDevice, stream);
  fill_kernel<<<(E + 255) / 256, 256, 0, stream>>>(src, dst, CURSOR, CSRSRC, E);

  // ---- weight transposes
  transpose_cat_kernel<<<128, 256, 0, stream>>>(W_l1, W_r1, WT1);
  transpose_cat_kernel<<<128, 256, 0, stream>>>(W_l2, W_r2, WT2);
  transpose_out_kernel<<<64, 256, 0, stream>>>(W_out, WTO);

  int ablocks = (N + 3) / 4;    // 4 nodes (waves) per block
  int lblocks = (N + 63) / 64;

  // layer 1
  agg_kernel<<<ablocks, 256, 0, stream>>>(x, CSRSRC, ROWSTART, DINV, AGG, N);
  lin_kernel<<<lblocks, 256, 0, stream>>>(AGG, x, WT1, b_l1, H, N);

  // layer 2 (agg into AGG, then lin writes h2 in-place into AGG)
  agg_kernel<<<ablocks, 256, 0, stream>>>(H, CSRSRC, ROWSTART, DINV, AGG, N);
  lin_kernel<<<lblocks, 256, 0, stream>>>(AGG, H, WT2, b_l2, AGG, N);

  // output projection
  out_kernel<<<lblocks, 256, 0, stream>>>(AGG, WTO, b_out, (float*)d_out, N);
}

// Round 3
// 627.584 us; speedup vs baseline: 9.3908x; 1.4486x over previous
//
#include <hip/hip_runtime.h>
#include <hip/hip_bf16.h>

#define HID 128
#define OUT_DIM 112

typedef short bf16x8 __attribute__((ext_vector_type(8)));
typedef float f32x4 __attribute__((ext_vector_type(4)));

__device__ __forceinline__ ushort f2b(float f) {
  __hip_bfloat16 h = __float2bfloat16(f);  // RNE
  return *reinterpret_cast<ushort*>(&h);
}

// ---- fp32 -> bf16 bulk convert (4 elems/thread)
__global__ __launch_bounds__(256) void f2b_kernel(
    const float* __restrict__ in, ushort* __restrict__ out, int n4) {
  int i = blockIdx.x * 256 + threadIdx.x;
  if (i >= n4) return;
  float4 v = ((const float4*)in)[i];
  ushort4 r;
  r.x = f2b(v.x); r.y = f2b(v.y); r.z = f2b(v.z); r.w = f2b(v.w);
  ((ushort4*)out)[i] = r;
}

// ---- pack W [nout x 128] fp32 into MFMA B-fragment order:
// wb[ks][nt][lane][j] = bf16( W[nt*16 + (lane&15)][ks*32 + (lane>>4)*8 + j] )
__global__ __launch_bounds__(256) void packw_kernel(
    const float* __restrict__ W, ushort* __restrict__ wb, int ntiles, int total) {
  int p = blockIdx.x * 256 + threadIdx.x;
  if (p >= total) return;
  int j = p & 7;
  int l = (p >> 3) & 63;
  int rest = p >> 9;
  int nt = rest % ntiles;
  int ks = rest / ntiles;
  int nn = nt * 16 + (l & 15);
  int k = ks * 32 + (l >> 4) * 8 + j;
  wb[p] = f2b(W[nn * 128 + k]);
}

// ---- CSR build step 1: integer degree count
__global__ __launch_bounds__(256) void deg_kernel(
    const int* __restrict__ dst, int* __restrict__ deg, int e) {
  int i = blockIdx.x * 256 + threadIdx.x;
  if (i < e) atomicAdd(&deg[dst[i]], 1);
}

// ---- CSR build step 2: exclusive prefix sum (single block, 1024 threads)
__global__ __launch_bounds__(1024) void scan_kernel(
    const int* __restrict__ deg, int* __restrict__ rowstart,
    float* __restrict__ dinv, int n) {
  __shared__ int wsum[16];
  __shared__ int carry_s;
  const int lane = threadIdx.x & 63;
  const int wid = threadIdx.x >> 6;
  if (threadIdx.x == 0) carry_s = 0;
  __syncthreads();
  for (int base = 0; base < n; base += 1024) {
    int i = base + threadIdx.x;
    int v = (i < n) ? deg[i] : 0;
    int s = v;
#pragma unroll
    for (int off = 1; off < 64; off <<= 1) {
      int t = __shfl_up(s, off, 64);
      if (lane >= off) s += t;
    }
    if (lane == 63) wsum[wid] = s;
    int c = carry_s;
    __syncthreads();
    if (wid == 0) {
      int ws = (lane < 16) ? wsum[lane] : 0;
#pragma unroll
      for (int off = 1; off < 16; off <<= 1) {
        int t = __shfl_up(ws, off, 64);
        if (lane >= off) ws += t;
      }
      if (lane < 16) wsum[lane] = ws;
    }
    __syncthreads();
    int wbase = (wid > 0) ? wsum[wid - 1] : 0;
    int incl = s + wbase;
    if (i < n) {
      rowstart[i] = c + incl - v;
      dinv[i] = 1.0f / (float)max(v, 1);
    }
    __syncthreads();
    if (threadIdx.x == 0) carry_s = c + wsum[15];
    __syncthreads();
  }
  if (threadIdx.x == 0) rowstart[n] = carry_s;
}

// ---- CSR build step 3: fill edge lists via atomic cursors
__global__ __launch_bounds__(256) void fill_kernel(
    const int* __restrict__ src, const int* __restrict__ dst,
    int* __restrict__ cursor, int* __restrict__ csr_src, int e) {
  int i = blockIdx.x * 256 + threadIdx.x;
  if (i < e) {
    int pos = atomicAdd(&cursor[dst[i]], 1);
    csr_src[pos] = src[i];
  }
}

// ---- gather-mean aggregation over bf16 rows: one wave/node, uint (2 bf16)/lane
__global__ __launch_bounds__(256) void agg_bf16_kernel(
    const ushort* __restrict__ xb, const int* __restrict__ csr_src,
    const int* __restrict__ rowstart, const float* __restrict__ dinv,
    ushort* __restrict__ aggb, int n) {
  int node = blockIdx.x * 4 + (threadIdx.x >> 6);
  int lane = threadIdx.x & 63;
  if (node >= n) return;
  int s = rowstart[node], e1 = rowstart[node + 1];
  float ax = 0.f, ay = 0.f;
  int e = s;
  for (; e + 4 <= e1; e += 4) {
    int s0 = csr_src[e], s1 = csr_src[e + 1], s2 = csr_src[e + 2], s3 = csr_src[e + 3];
    uint u0 = ((const uint*)(xb + (size_t)s0 * 128))[lane];
    uint u1 = ((const uint*)(xb + (size_t)s1 * 128))[lane];
    uint u2 = ((const uint*)(xb + (size_t)s2 * 128))[lane];
    uint u3 = ((const uint*)(xb + (size_t)s3 * 128))[lane];
    ax += (__uint_as_float(u0 << 16) + __uint_as_float(u1 << 16)) +
          (__uint_as_float(u2 << 16) + __uint_as_float(u3 << 16));
    ay += (__uint_as_float(u0 & 0xffff0000u) + __uint_as_float(u1 & 0xffff0000u)) +
          (__uint_as_float(u2 & 0xffff0000u) + __uint_as_float(u3 & 0xffff0000u));
  }
  for (; e < e1; ++e) {
    uint u = ((const uint*)(xb + (size_t)csr_src[e] * 128))[lane];
    ax += __uint_as_float(u << 16);
    ay += __uint_as_float(u & 0xffff0000u);
  }
  float sc = dinv[node];
  uint r = (uint)f2b(ax * sc) | ((uint)f2b(ay * sc) << 16);
  ((uint*)(aggb + (size_t)node * 128))[lane] = r;
}

// ---- fused SAGE linear via MFMA:
// out = bf16( relu( mean @ Wl^T + b + x @ Wr^T ) ), all operands bf16, fp32 acc.
// Block: 256 thr (4 waves), M-tile 64 nodes; wave computes 16 rows x 128 cols.
// wb layout: [s][ks][nt][lane][j] fragment-packed (s=0: W_l, s=1: W_r).
__global__ __launch_bounds__(256) void lin_mfma_kernel(
    const ushort* __restrict__ meanb, const ushort* __restrict__ xb,
    const ushort* __restrict__ wb, const float* __restrict__ bias,
    ushort* __restrict__ outb, int n) {
  __shared__ ushort zA[64 * 128];
  __shared__ ushort zX[64 * 128];
  const int t = threadIdx.x;
  const int block0 = blockIdx.x * 64;
#pragma unroll
  for (int i = 0; i < 4; ++i) {
    int c = i * 256 + t;      // 16B chunk id (1024/tile)
    int row = c >> 4;
    int col = c & 15;
    int node = block0 + row;
    int4 va = make_int4(0, 0, 0, 0), vx = make_int4(0, 0, 0, 0);
    if (node < n) {
      va = ((const int4*)(meanb + (size_t)node * 128))[col];
      vx = ((const int4*)(xb + (size_t)node * 128))[col];
    }
    ((int4*)zA)[c] = va;
    ((int4*)zX)[c] = vx;
  }
  __syncthreads();
  const int lane = t & 63;
  const int wave = t >> 6;
  const int m0 = wave * 16;
  const int cidx = lane & 15;  // A-row / D-col
  const int quad = lane >> 4;
  f32x4 acc[8];
#pragma unroll
  for (int nt = 0; nt < 8; ++nt) acc[nt] = (f32x4){0.f, 0.f, 0.f, 0.f};
  const ushort* zsrc0 = zA;
  const ushort* zsrc1 = zX;
#pragma unroll
  for (int s = 0; s < 2; ++s) {
    const ushort* zs = (s == 0) ? zsrc0 : zsrc1;
#pragma unroll
    for (int ks = 0; ks < 4; ++ks) {
      bf16x8 a = *(const bf16x8*)(zs + (m0 + cidx) * 128 + ks * 32 + quad * 8);
      const ushort* wp = wb + ((size_t)((s * 4 + ks) * 8) * 64 + lane) * 8;
#pragma unroll
      for (int nt = 0; nt < 8; ++nt) {
        bf16x8 b = *(const bf16x8*)(wp + nt * 512);
        acc[nt] = __builtin_amdgcn_mfma_f32_16x16x32_bf16(a, b, acc[nt], 0, 0, 0);
      }
    }
  }
  __syncthreads();
  // epilogue: bias + relu -> bf16 staged in zA, then coalesced store
#pragma unroll
  for (int nt = 0; nt < 8; ++nt) {
    float bv = bias[nt * 16 + cidx];
#pragma unroll
    for (int i = 0; i < 4; ++i) {
      float v = fmaxf(acc[nt][i] + bv, 0.f);
      zA[(m0 + quad * 4 + i) * 128 + nt * 16 + cidx] = f2b(v);
    }
  }
  __syncthreads();
#pragma unroll
  for (int i = 0; i < 4; ++i) {
    int c = i * 256 + t;
    int row = c >> 4;
    int col = c & 15;
    int node = block0 + row;
    if (node < n) ((int4*)(outb + (size_t)node * 128))[col] = ((const int4*)zA)[c];
  }
}

// ---- output projection via MFMA: out = h2 @ W_out^T + b_out, fp32 out [n x 112]
__global__ __launch_bounds__(256) void out_mfma_kernel(
    const ushort* __restrict__ h2b, const ushort* __restrict__ wb,
    const float* __restrict__ bias, float* __restrict__ outp, int n) {
  __shared__ ushort zt[64 * 128];
  __shared__ float zo[64 * 112];
  const int t = threadIdx.x;
  const int block0 = blockIdx.x * 64;
#pragma unroll
  for (int i = 0; i < 4; ++i) {
    int c = i * 256 + t;
    int row = c >> 4;
    int col = c & 15;
    int node = block0 + row;
    int4 v = make_int4(0, 0, 0, 0);
    if (node < n) v = ((const int4*)(h2b + (size_t)node * 128))[col];
    ((int4*)zt)[c] = v;
  }
  __syncthreads();
  const int lane = t & 63;
  const int wave = t >> 6;
  const int m0 = wave * 16;
  const int cidx = lane & 15;
  const int quad = lane >> 4;
  f32x4 acc[7];
#pragma unroll
  for (int nt = 0; nt < 7; ++nt) acc[nt] = (f32x4){0.f, 0.f, 0.f, 0.f};
#pragma unroll
  for (int ks = 0; ks < 4; ++ks) {
    bf16x8 a = *(const bf16x8*)(zt + (m0 + cidx) * 128 + ks * 32 + quad * 8);
    const ushort* wp = wb + ((size_t)(ks * 7) * 64 + lane) * 8;
#pragma unroll
    for (int nt = 0; nt < 7; ++nt) {
      bf16x8 b = *(const bf16x8*)(wp + nt * 512);
      acc[nt] = __builtin_amdgcn_mfma_f32_16x16x32_bf16(a, b, acc[nt], 0, 0, 0);
    }
  }
#pragma unroll
  for (int nt = 0; nt < 7; ++nt) {
    float bv = bias[nt * 16 + cidx];
#pragma unroll
    for (int i = 0; i < 4; ++i)
      zo[(m0 + quad * 4 + i) * 112 + nt * 16 + cidx] = acc[nt][i] + bv;
  }
  __syncthreads();
  // 64x112 fp32 tile is contiguous in outp -> linear coalesced copy (1792 f4)
#pragma unroll
  for (int i = 0; i < 7; ++i) {
    int c = i * 256 + t;
    int node = block0 + c / 28;  // 28 float4 per row
    if (node < n)
      ((float4*)(outp + (size_t)block0 * 112))[c] = ((const float4*)zo)[c];
  }
}

extern "C" void kernel_launch(void* const* d_in, const int* in_sizes, int n_in,
                              void* d_out, int out_size, void* d_ws, size_t ws_size,
                              hipStream_t stream) {
  const float* x     = (const float*)d_in[0];
  const int*   ei    = (const int*)d_in[1];
  const float* W_l1  = (const float*)d_in[2];
  const float* b_l1  = (const float*)d_in[3];
  const float* W_r1  = (const float*)d_in[4];
  const float* W_l2  = (const float*)d_in[5];
  const float* b_l2  = (const float*)d_in[6];
  const float* W_r2  = (const float*)d_in[7];
  const float* W_out = (const float*)d_in[8];
  const float* b_out = (const float*)d_in[9];

  const int N = in_sizes[0] / 128;
  const int E = in_sizes[1] / 2;
  const int* src = ei;
  const int* dst = ei + E;

  ushort* XB = (ushort*)d_ws;               // N*128 bf16 (x, later h2)
  ushort* MB = XB + (size_t)N * 128;        // N*128 bf16 (mean)
  ushort* HB = MB + (size_t)N * 128;        // N*128 bf16 (h1)
  float* DINV = (float*)(HB + (size_t)N * 128);  // N f32
  ushort* WB1 = (ushort*)(DINV + N);        // 2*4*8*64*8 = 32768
  ushort* WB2 = WB1 + 32768;                // 32768
  ushort* WBO = WB2 + 32768;                // 4*7*64*8 = 14336
  int* DEG      = (int*)(WBO + 14336);      // N
  int* ROWSTART = DEG + N;                  // N+1
  int* CURSOR   = ROWSTART + N + 1;         // N
  int* CSRSRC   = CURSOR + N;               // E

  // ---- CSR build (reused by both layers)
  hipMemsetAsync(DEG, 0, (size_t)N * sizeof(int), stream);
  deg_kernel<<<(E + 255) / 256, 256, 0, stream>>>(dst, DEG, E);
  scan_kernel<<<1, 1024, 0, stream>>>(DEG, ROWSTART, DINV, N);
  hipMemcpyAsync(CURSOR, ROWSTART, (size_t)N * sizeof(int),
                 hipMemcpyDeviceToDevice, stream);
  fill_kernel<<<(E + 255) / 256, 256, 0, stream>>>(src, dst, CURSOR, CSRSRC, E);

  // ---- x -> bf16, weight fragment packing
  int n4 = N * 128 / 4;
  f2b_kernel<<<(n4 + 255) / 256, 256, 0, stream>>>(x, XB, n4);
  packw_kernel<<<64, 256, 0, stream>>>(W_l1, WB1, 8, 16384);
  packw_kernel<<<64, 256, 0, stream>>>(W_r1, WB1 + 16384, 8, 16384);
  packw_kernel<<<64, 256, 0, stream>>>(W_l2, WB2, 8, 16384);
  packw_kernel<<<64, 256, 0, stream>>>(W_r2, WB2 + 16384, 8, 16384);
  packw_kernel<<<56, 256, 0, stream>>>(W_out, WBO, 7, 14336);

  int ablocks = (N + 3) / 4;
  int lblocks = (N + 63) / 64;

  // layer 1: mean(x) -> MB; h1 = relu(lin) -> HB
  agg_bf16_kernel<<<ablocks, 256, 0, stream>>>(XB, CSRSRC, ROWSTART, DINV, MB, N);
  lin_mfma_kernel<<<lblocks, 256, 0, stream>>>(MB, XB, WB1, b_l1, HB, N);

  // layer 2: mean(h1) -> MB; h2 -> XB (x no longer needed)
  agg_bf16_kernel<<<ablocks, 256, 0, stream>>>(HB, CSRSRC, ROWSTART, DINV, MB, N);
  lin_mfma_kernel<<<lblocks, 256, 0, stream>>>(MB, HB, WB2, b_l2, XB, N);

  // output projection
  out_mfma_kernel<<<lblocks, 256, 0, stream>>>(XB, WBO, b_out, (float*)d_out, N);
}

// Round 4
// 375.491 us; speedup vs baseline: 15.6955x; 1.6714x over previous
//
#include <hip/hip_runtime.h>
#include <hip/hip_bf16.h>

#define HID 128
#define OUT_DIM 112
#define CAP 4096

typedef short bf16x8 __attribute__((ext_vector_type(8)));
typedef float f32x4 __attribute__((ext_vector_type(4)));

__device__ __forceinline__ ushort f2b(float f) {
  __hip_bfloat16 h = __float2bfloat16(f);  // RNE
  return *reinterpret_cast<ushort*>(&h);
}

// ---- fp32 -> bf16 bulk convert (4 elems/thread)
__global__ __launch_bounds__(256) void f2b_kernel(
    const float* __restrict__ in, ushort* __restrict__ out, int n4) {
  int i = blockIdx.x * 256 + threadIdx.x;
  if (i >= n4) return;
  float4 v = ((const float4*)in)[i];
  ushort4 r;
  r.x = f2b(v.x); r.y = f2b(v.y); r.z = f2b(v.z); r.w = f2b(v.w);
  ((ushort4*)out)[i] = r;
}

// ---- pack W [nout x 128] fp32 into MFMA B-fragment order:
// wb[ks][nt][lane][j] = bf16( W[nt*16 + (lane&15)][ks*32 + (lane>>4)*8 + j] )
__global__ __launch_bounds__(256) void packw_kernel(
    const float* __restrict__ W, ushort* __restrict__ wb, int ntiles, int total) {
  int p = blockIdx.x * 256 + threadIdx.x;
  if (p >= total) return;
  int j = p & 7;
  int l = (p >> 3) & 63;
  int rest = p >> 9;
  int nt = rest % ntiles;
  int ks = rest / ntiles;
  int nn = nt * 16 + (l & 15);
  int k = ks * 32 + (l >> 4) * 8 + j;
  wb[p] = f2b(W[nn * 128 + k]);
}

// ---- sort pass 0: per-block LDS histogram of dst>>7, merged to global
__global__ __launch_bounds__(256) void hist_kernel(
    const int* __restrict__ dst, int* __restrict__ gcount, int e, int nb) {
  __shared__ int lh[1024];
  const int t = threadIdx.x;
  for (int i = t; i < nb; i += 256) lh[i] = 0;
  __syncthreads();
  int base = blockIdx.x * 4096;
#pragma unroll
  for (int j = 0; j < 16; ++j) {
    int i = base + j * 256 + t;
    if (i < e) atomicAdd(&lh[dst[i] >> 7], 1);
  }
  __syncthreads();
  for (int i = t; i < nb; i += 256)
    if (lh[i]) atomicAdd(&gcount[i], lh[i]);
}

// ---- sort pass 1: scan bucket counts -> bases + cursors; rowstart[n]=e
__global__ __launch_bounds__(1024) void scan_nb_kernel(
    const int* __restrict__ gcount, int* __restrict__ gbase,
    int* __restrict__ gcursor, int* __restrict__ rowstart,
    int e, int n, int nb) {
  __shared__ int wsum[16];
  const int t = threadIdx.x, lane = t & 63, wid = t >> 6;
  int v = (t < nb) ? gcount[t] : 0;
  int s = v;
#pragma unroll
  for (int off = 1; off < 64; off <<= 1) {
    int u = __shfl_up(s, off, 64);
    if (lane >= off) s += u;
  }
  if (lane == 63) wsum[wid] = s;
  __syncthreads();
  if (wid == 0) {
    int ws = (lane < 16) ? wsum[lane] : 0;
#pragma unroll
    for (int off = 1; off < 16; off <<= 1) {
      int u = __shfl_up(ws, off, 64);
      if (lane >= off) ws += u;
    }
    if (lane < 16) wsum[lane] = ws;
  }
  __syncthreads();
  int excl = s - v + (wid ? wsum[wid - 1] : 0);
  if (t < nb) {
    gbase[t] = excl;
    gcursor[t] = excl;
  }
  if (t == 0) {
    gbase[nb] = e;
    rowstart[n] = e;
  }
}

// ---- sort pass 2: bucket edges; write packed (src<<7)|(dst&127) in
// bucket-grouped order. One global atomic per (block,bucket); LDS reorder
// makes writes runs of ~10 consecutive entries.
__global__ __launch_bounds__(1024) void bucket_scatter_kernel(
    const int* __restrict__ src, const int* __restrict__ dst,
    int* __restrict__ gcursor, uint* __restrict__ bedges, int e, int nb) {
  __shared__ int lh[1024];     // hist, then reused as global run base
  __shared__ int lstart[1024]; // local exclusive scan
  __shared__ int wsum[16];
  __shared__ uint sp[8192];
  __shared__ ushort sb[8192];
  const int t = threadIdx.x, lane = t & 63, wid = t >> 6;
  const int base = blockIdx.x * 8192;
  const int ecnt = min(8192, e - base);
  for (int i = t; i < nb; i += 1024) lh[i] = 0;
  __syncthreads();
  int myb[8], myr[8];
  uint myp[8];
#pragma unroll
  for (int j = 0; j < 8; ++j) {
    int i = base + j * 1024 + t;
    myb[j] = -1;
    if (i < e) {
      int d = dst[i];
      int sv = src[i];
      int b = d >> 7;
      myb[j] = b;
      myp[j] = ((uint)sv << 7) | (uint)(d & 127);
      myr[j] = atomicAdd(&lh[b], 1);
    }
  }
  __syncthreads();
  int cnt = (t < nb) ? lh[t] : 0;
  int s = cnt;
#pragma unroll
  for (int off = 1; off < 64; off <<= 1) {
    int u = __shfl_up(s, off, 64);
    if (lane >= off) s += u;
  }
  if (lane == 63) wsum[wid] = s;
  __syncthreads();
  if (wid == 0) {
    int ws = (lane < 16) ? wsum[lane] : 0;
#pragma unroll
    for (int off = 1; off < 16; off <<= 1) {
      int u = __shfl_up(ws, off, 64);
      if (lane >= off) ws += u;
    }
    if (lane < 16) wsum[lane] = ws;
  }
  __syncthreads();
  int excl = s - cnt + (wid ? wsum[wid - 1] : 0);
  if (t < nb) lstart[t] = excl;
  __syncthreads();
  if (t < nb) lh[t] = (cnt > 0) ? atomicAdd(&gcursor[t], cnt) : 0;
  __syncthreads();
#pragma unroll
  for (int j = 0; j < 8; ++j) {
    if (myb[j] >= 0) {
      int slot = lstart[myb[j]] + myr[j];
      sp[slot] = myp[j];
      sb[slot] = (ushort)myb[j];
    }
  }
  __syncthreads();
#pragma unroll
  for (int j = 0; j < 8; ++j) {
    int i = j * 1024 + t;
    if (i < ecnt) {
      int b = sb[i];
      int pos = lh[b] + (i - lstart[b]);
      bedges[pos] = sp[i];
    }
  }
}

// ---- sort pass 3: per-bucket counting sort by dst&127 -> csr_src,
// rowstart, dinv. All global writes coalesced.
__global__ __launch_bounds__(256) void csr_build_kernel(
    const uint* __restrict__ bedges, const int* __restrict__ gbase,
    int* __restrict__ rowstart, float* __restrict__ dinv,
    int* __restrict__ csr_src, int n) {
  __shared__ int lh[128];
  __shared__ int lst[128];
  __shared__ int lcur[128];
  __shared__ int wsum2[4];
  __shared__ int lsorted[CAP];
  const int t = threadIdx.x;
  const int bkt = blockIdx.x;
  const int node0 = bkt << 7;
  const int g0 = gbase[bkt], g1 = gbase[bkt + 1];
  const int cnt = g1 - g0;
  if (t < 128) lh[t] = 0;
  __syncthreads();
  for (int i = t; i < cnt; i += 256)
    atomicAdd(&lh[bedges[g0 + i] & 127], 1);
  __syncthreads();
  const int lane = t & 63, wid = t >> 6;
  int v = (t < 128) ? lh[t] : 0;
  int s = v;
#pragma unroll
  for (int off = 1; off < 64; off <<= 1) {
    int u = __shfl_up(s, off, 64);
    if (lane >= off) s += u;
  }
  if (t < 128 && lane == 63) wsum2[wid] = s;
  __syncthreads();
  int excl = s - v + ((wid == 1) ? wsum2[0] : 0);
  if (t < 128) {
    lst[t] = excl;
    lcur[t] = excl;
    int node = node0 + t;
    if (node < n) {
      rowstart[node] = g0 + excl;
      dinv[node] = 1.0f / (float)max(v, 1);
    }
  }
  __syncthreads();
  for (int i = t; i < cnt; i += 256) {
    uint p = bedges[g0 + i];
    int d = p & 127;
    int slot = atomicAdd(&lcur[d], 1);
    int sv = (int)(p >> 7);
    if (slot < CAP) lsorted[slot] = sv;
    else csr_src[g0 + slot] = sv;  // statistically never (cnt ~2050, 45 sigma)
  }
  __syncthreads();
  int lim = min(cnt, CAP);
  for (int i = t; i < lim; i += 256) csr_src[g0 + i] = lsorted[i];
}

// ---- gather-mean aggregation over bf16 rows: one wave/node, uint (2 bf16)/lane
__global__ __launch_bounds__(256) void agg_bf16_kernel(
    const ushort* __restrict__ xb, const int* __restrict__ csr_src,
    const int* __restrict__ rowstart, const float* __restrict__ dinv,
    ushort* __restrict__ aggb, int n) {
  int node = blockIdx.x * 4 + (threadIdx.x >> 6);
  int lane = threadIdx.x & 63;
  if (node >= n) return;
  int s = rowstart[node], e1 = rowstart[node + 1];
  float ax = 0.f, ay = 0.f;
  int e = s;
  for (; e + 4 <= e1; e += 4) {
    int s0 = csr_src[e], s1 = csr_src[e + 1], s2 = csr_src[e + 2], s3 = csr_src[e + 3];
    uint u0 = ((const uint*)(xb + (size_t)s0 * 128))[lane];
    uint u1 = ((const uint*)(xb + (size_t)s1 * 128))[lane];
    uint u2 = ((const uint*)(xb + (size_t)s2 * 128))[lane];
    uint u3 = ((const uint*)(xb + (size_t)s3 * 128))[lane];
    ax += (__uint_as_float(u0 << 16) + __uint_as_float(u1 << 16)) +
          (__uint_as_float(u2 << 16) + __uint_as_float(u3 << 16));
    ay += (__uint_as_float(u0 & 0xffff0000u) + __uint_as_float(u1 & 0xffff0000u)) +
          (__uint_as_float(u2 & 0xffff0000u) + __uint_as_float(u3 & 0xffff0000u));
  }
  for (; e < e1; ++e) {
    uint u = ((const uint*)(xb + (size_t)csr_src[e] * 128))[lane];
    ax += __uint_as_float(u << 16);
    ay += __uint_as_float(u & 0xffff0000u);
  }
  float sc = dinv[node];
  uint r = (uint)f2b(ax * sc) | ((uint)f2b(ay * sc) << 16);
  ((uint*)(aggb + (size_t)node * 128))[lane] = r;
}

// ---- fused SAGE linear via MFMA (bf16 in, fp32 acc, bf16 out)
__global__ __launch_bounds__(256) void lin_mfma_kernel(
    const ushort* __restrict__ meanb, const ushort* __restrict__ xb,
    const ushort* __restrict__ wb, const float* __restrict__ bias,
    ushort* __restrict__ outb, int n) {
  __shared__ ushort zA[64 * 128];
  __shared__ ushort zX[64 * 128];
  const int t = threadIdx.x;
  const int block0 = blockIdx.x * 64;
#pragma unroll
  for (int i = 0; i < 4; ++i) {
    int c = i * 256 + t;
    int row = c >> 4;
    int col = c & 15;
    int node = block0 + row;
    int4 va = make_int4(0, 0, 0, 0), vx = make_int4(0, 0, 0, 0);
    if (node < n) {
      va = ((const int4*)(meanb + (size_t)node * 128))[col];
      vx = ((const int4*)(xb + (size_t)node * 128))[col];
    }
    ((int4*)zA)[c] = va;
    ((int4*)zX)[c] = vx;
  }
  __syncthreads();
  const int lane = t & 63;
  const int wave = t >> 6;
  const int m0 = wave * 16;
  const int cidx = lane & 15;
  const int quad = lane >> 4;
  f32x4 acc[8];
#pragma unroll
  for (int nt = 0; nt < 8; ++nt) acc[nt] = (f32x4){0.f, 0.f, 0.f, 0.f};
#pragma unroll
  for (int s = 0; s < 2; ++s) {
    const ushort* zs = (s == 0) ? zA : zX;
#pragma unroll
    for (int ks = 0; ks < 4; ++ks) {
      bf16x8 a = *(const bf16x8*)(zs + (m0 + cidx) * 128 + ks * 32 + quad * 8);
      const ushort* wp = wb + ((size_t)((s * 4 + ks) * 8) * 64 + lane) * 8;
#pragma unroll
      for (int nt = 0; nt < 8; ++nt) {
        bf16x8 b = *(const bf16x8*)(wp + nt * 512);
        acc[nt] = __builtin_amdgcn_mfma_f32_16x16x32_bf16(a, b, acc[nt], 0, 0, 0);
      }
    }
  }
  __syncthreads();
#pragma unroll
  for (int nt = 0; nt < 8; ++nt) {
    float bv = bias[nt * 16 + cidx];
#pragma unroll
    for (int i = 0; i < 4; ++i) {
      float v = fmaxf(acc[nt][i] + bv, 0.f);
      zA[(m0 + quad * 4 + i) * 128 + nt * 16 + cidx] = f2b(v);
    }
  }
  __syncthreads();
#pragma unroll
  for (int i = 0; i < 4; ++i) {
    int c = i * 256 + t;
    int row = c >> 4;
    int col = c & 15;
    int node = block0 + row;
    if (node < n) ((int4*)(outb + (size_t)node * 128))[col] = ((const int4*)zA)[c];
  }
}

// ---- output projection via MFMA: out = h2 @ W_out^T + b_out, fp32 [n x 112]
__global__ __launch_bounds__(256) void out_mfma_kernel(
    const ushort* __restrict__ h2b, const ushort* __restrict__ wb,
    const float* __restrict__ bias, float* __restrict__ outp, int n) {
  __shared__ ushort zt[64 * 128];
  __shared__ float zo[64 * 112];
  const int t = threadIdx.x;
  const int block0 = blockIdx.x * 64;
#pragma unroll
  for (int i = 0; i < 4; ++i) {
    int c = i * 256 + t;
    int row = c >> 4;
    int col = c & 15;
    int node = block0 + row;
    int4 v = make_int4(0, 0, 0, 0);
    if (node < n) v = ((const int4*)(h2b + (size_t)node * 128))[col];
    ((int4*)zt)[c] = v;
  }
  __syncthreads();
  const int lane = t & 63;
  const int wave = t >> 6;
  const int m0 = wave * 16;
  const int cidx = lane & 15;
  const int quad = lane >> 4;
  f32x4 acc[7];
#pragma unroll
  for (int nt = 0; nt < 7; ++nt) acc[nt] = (f32x4){0.f, 0.f, 0.f, 0.f};
#pragma unroll
  for (int ks = 0; ks < 4; ++ks) {
    bf16x8 a = *(const bf16x8*)(zt + (m0 + cidx) * 128 + ks * 32 + quad * 8);
    const ushort* wp = wb + ((size_t)(ks * 7) * 64 + lane) * 8;
#pragma unroll
    for (int nt = 0; nt < 7; ++nt) {
      bf16x8 b = *(const bf16x8*)(wp + nt * 512);
      acc[nt] = __builtin_amdgcn_mfma_f32_16x16x32_bf16(a, b, acc[nt], 0, 0, 0);
    }
  }
#pragma unroll
  for (int nt = 0; nt < 7; ++nt) {
    float bv = bias[nt * 16 + cidx];
#pragma unroll
    for (int i = 0; i < 4; ++i)
      zo[(m0 + quad * 4 + i) * 112 + nt * 16 + cidx] = acc[nt][i] + bv;
  }
  __syncthreads();
#pragma unroll
  for (int i = 0; i < 7; ++i) {
    int c = i * 256 + t;
    int node = block0 + c / 28;
    if (node < n)
      ((float4*)(outp + (size_t)block0 * 112))[c] = ((const float4*)zo)[c];
  }
}

extern "C" void kernel_launch(void* const* d_in, const int* in_sizes, int n_in,
                              void* d_out, int out_size, void* d_ws, size_t ws_size,
                              hipStream_t stream) {
  const float* x     = (const float*)d_in[0];
  const int*   ei    = (const int*)d_in[1];
  const float* W_l1  = (const float*)d_in[2];
  const float* b_l1  = (const float*)d_in[3];
  const float* W_r1  = (const float*)d_in[4];
  const float* W_l2  = (const float*)d_in[5];
  const float* b_l2  = (const float*)d_in[6];
  const float* W_r2  = (const float*)d_in[7];
  const float* W_out = (const float*)d_in[8];
  const float* b_out = (const float*)d_in[9];

  const int N = in_sizes[0] / 128;
  const int E = in_sizes[1] / 2;
  const int NB = (N + 127) >> 7;
  const int* src = ei;
  const int* dst = ei + E;

  ushort* XB = (ushort*)d_ws;               // N*128 bf16 (x, later h2)
  ushort* MB = XB + (size_t)N * 128;        // N*128 bf16 (mean)
  ushort* HB = MB + (size_t)N * 128;        // N*128 bf16 (h1)
  float* DINV = (float*)(HB + (size_t)N * 128);  // N f32
  ushort* WB1 = (ushort*)(DINV + N);        // 32768
  ushort* WB2 = WB1 + 32768;                // 32768
  ushort* WBO = WB2 + 32768;                // 14336
  int* GCOUNT   = (int*)(WBO + 14336);      // NB
  int* GBASE    = GCOUNT + NB;              // NB+1
  int* GCURSOR  = GBASE + NB + 1;           // NB
  int* ROWSTART = GCURSOR + NB;             // N+1
  uint* BEDGES  = (uint*)(ROWSTART + N + 1);// E
  int* CSRSRC   = (int*)(BEDGES + E);       // E

  // ---- CSR build via two-pass counting sort
  hipMemsetAsync(GCOUNT, 0, (size_t)NB * sizeof(int), stream);
  hist_kernel<<<(E + 4095) / 4096, 256, 0, stream>>>(dst, GCOUNT, E, NB);
  scan_nb_kernel<<<1, 1024, 0, stream>>>(GCOUNT, GBASE, GCURSOR, ROWSTART, E, N, NB);
  bucket_scatter_kernel<<<(E + 8191) / 8192, 1024, 0, stream>>>(
      src, dst, GCURSOR, BEDGES, E, NB);
  csr_build_kernel<<<NB, 256, 0, stream>>>(BEDGES, GBASE, ROWSTART, DINV, CSRSRC, N);

  // ---- x -> bf16, weight fragment packing
  int n4 = N * 128 / 4;
  f2b_kernel<<<(n4 + 255) / 256, 256, 0, stream>>>(x, XB, n4);
  packw_kernel<<<64, 256, 0, stream>>>(W_l1, WB1, 8, 16384);
  packw_kernel<<<64, 256, 0, stream>>>(W_r1, WB1 + 16384, 8, 16384);
  packw_kernel<<<64, 256, 0, stream>>>(W_l2, WB2, 8, 16384);
  packw_kernel<<<64, 256, 0, stream>>>(W_r2, WB2 + 16384, 8, 16384);
  packw_kernel<<<56, 256, 0, stream>>>(W_out, WBO, 7, 14336);

  int ablocks = (N + 3) / 4;
  int lblocks = (N + 63) / 64;

  // layer 1
  agg_bf16_kernel<<<ablocks, 256, 0, stream>>>(XB, CSRSRC, ROWSTART, DINV, MB, N);
  lin_mfma_kernel<<<lblocks, 256, 0, stream>>>(MB, XB, WB1, b_l1, HB, N);

  // layer 2 (h2 -> XB; x no longer needed)
  agg_bf16_kernel<<<ablocks, 256, 0, stream>>>(HB, CSRSRC, ROWSTART, DINV, MB, N);
  lin_mfma_kernel<<<lblocks, 256, 0, stream>>>(MB, HB, WB2, b_l2, XB, N);

  // output projection
  out_mfma_kernel<<<lblocks, 256, 0, stream>>>(XB, WBO, b_out, (float*)d_out, N);
}